// Round 1
// baseline (469.724 us; speedup 1.0000x reference)
//
#include <hip/hip_runtime.h>

constexpr int N_NODES = 500000;
constexpr int N_Q     = 500000;
constexpr int H       = 8;
constexpr int FEAT    = 64;                       // H * MH

// ---- binning parameters -----------------------------------------------------
constexpr int TBIN   = 64;                        // nodes per bin
constexpr int SHIFT  = 6;                         // log2(TBIN)
constexpr int NB     = (N_NODES + TBIN - 1) / TBIN;   // 7813 bins
constexpr int NB_PAD = 8192;                      // scan width (1024 thr x 8)
constexpr int TP     = TBIN + 1;                  // 65: odd pad -> bank (f+dj)%32

// ---------------------------------------------------------------------------
// K0: zero the histogram (workspace is re-poisoned between iterations).
// ---------------------------------------------------------------------------
__global__ __launch_bounds__(256) void zero_hist(int* __restrict__ hist)
{
    const int i = blockIdx.x * 256 + threadIdx.x;
    if (i < NB_PAD) hist[i] = 0;
}

// ---------------------------------------------------------------------------
// K1: histogram of k_indices into node bins.
// ---------------------------------------------------------------------------
__global__ __launch_bounds__(256) void hist_kernel(const int* __restrict__ k_idx,
                                                   int* __restrict__ hist)
{
    int i = blockIdx.x * blockDim.x + threadIdx.x;
    const int stride = gridDim.x * blockDim.x;
    for (; i < N_Q; i += stride)
        atomicAdd(&hist[k_idx[i] >> SHIFT], 1);
}

// ---------------------------------------------------------------------------
// K2: single-block exclusive scan over NB_PAD bins -> offsets (NB+1) & cursor.
// 1024 threads x 8 sequential elements, Hillis-Steele over per-thread sums.
// ---------------------------------------------------------------------------
__global__ __launch_bounds__(1024) void scan_kernel(const int* __restrict__ hist,
                                                    int* __restrict__ offsets,
                                                    int* __restrict__ cursor)
{
    __shared__ int sums[1024];
    const int tid  = threadIdx.x;
    const int base = tid * 8;

    int loc[8];
    int run = 0;
#pragma unroll
    for (int k = 0; k < 8; ++k) {
        loc[k] = run;
        const int idx = base + k;
        run += (idx < NB) ? hist[idx] : 0;
    }
    sums[tid] = run;
    __syncthreads();

    const int own = run;
    for (int d = 1; d < 1024; d <<= 1) {
        const int add = (tid >= d) ? sums[tid - d] : 0;
        __syncthreads();
        sums[tid] += add;
        __syncthreads();
    }
    const int excl = sums[tid] - own;        // exclusive prefix of this thread's chunk

#pragma unroll
    for (int k = 0; k < 8; ++k) {
        const int idx = base + k;
        if (idx <= NB) {                     // offsets[NB] = N_Q (end sentinel)
            const int v = excl + loc[k];
            offsets[idx] = v;
            cursor[idx]  = v;
        }
    }
}

// ---------------------------------------------------------------------------
// K3: scatter packed (q << 6 | dj) into bin-sorted order.
// q < 2^19, dj < 2^6 -> fits u32. Order within a bin is nondeterministic but
// irrelevant: each query writes only its own output slots.
// ---------------------------------------------------------------------------
__global__ __launch_bounds__(256) void scatter_kernel(const int* __restrict__ k_idx,
                                                      int* __restrict__ cursor,
                                                      unsigned* __restrict__ vals)
{
    int i = blockIdx.x * blockDim.x + threadIdx.x;
    const int stride = gridDim.x * blockDim.x;
    for (; i < N_Q; i += stride) {
        const int j = k_idx[i];
        const int b = j >> SHIFT;
        const int p = atomicAdd(&cursor[b], 1);
        vals[p] = ((unsigned)i << SHIFT) | (unsigned)(j & (TBIN - 1));
    }
}

// ---------------------------------------------------------------------------
// K4: main binned kernel. One block per 64-node bin:
//   stage phi_k_pos/neg columns for the bin into LDS (coalesced 256B rows),
//   then serve the bin's queries: thread = (query-slot, head).
// LDS layout [2][64 feat][65]: compute-read bank = (8h+k+dj)%32 -> 2-way (free);
// staging-write bank = (f+4t+k)%32 -> ~4-way (cheap, hidden under HBM stream).
// ---------------------------------------------------------------------------
__global__ __launch_bounds__(256, 4) void iskde_binned(
    const float* __restrict__ q_phi,
    const float* __restrict__ pk_pos,                 // [64][N_NODES]
    const float* __restrict__ pk_neg,
    const float* __restrict__ deg_pos,                // [N_NODES][H]
    const float* __restrict__ deg_neg,
    const unsigned* __restrict__ vals,                // bin-sorted (q<<6|dj)
    const int* __restrict__ offsets,                  // [NB+1]
    float* __restrict__ out)                          // [2][N_Q][H]
{
    __shared__ float lds[2][FEAT][TP];                // 33,280 B -> 4 blocks/CU

    const int tid  = threadIdx.x;
    const int b    = blockIdx.x;
    const int n0   = b * TBIN;
    const int nrem = min(TBIN, N_NODES - n0);

    // ---- stage the bin's phi_k columns (pos & neg) ----
#pragma unroll
    for (int s = 0; s < 2; ++s) {
        const float* __restrict__ src = s ? pk_neg : pk_pos;
#pragma unroll
        for (int it = 0; it < 4; ++it) {
            const int g  = it * 256 + tid;            // 0..1023
            const int f  = g >> 4;                    // 0..63
            const int n4 = (g & 15) * 4;              // 0..60
            const float* p = src + (size_t)f * N_NODES + n0 + n4;
            float4 v = make_float4(0.f, 0.f, 0.f, 0.f);
            if (n4 + 3 < nrem) {
                v = *(const float4*)p;
            } else {
                if (n4 + 0 < nrem) v.x = p[0];
                if (n4 + 1 < nrem) v.y = p[1];
                if (n4 + 2 < nrem) v.z = p[2];
                if (n4 + 3 < nrem) v.w = p[3];
            }
            float* l = &lds[s][f][n4];
            l[0] = v.x; l[1] = v.y; l[2] = v.z; l[3] = v.w;
        }
    }
    __syncthreads();

    const int start = offsets[b];
    const int count = offsets[b + 1] - start;
    const int h    = tid & 7;
    const int slot = tid >> 3;                        // 0..31 queries per sweep

    for (int it0 = 0; it0 < count; it0 += 32) {
        const int qi    = it0 + slot;
        const bool valid = qi < count;
        unsigned v = 0;
        if (valid) v = vals[start + qi];
        const int q  = (int)(v >> SHIFT);             // invalid lanes -> q=0 (safe)
        const int dj = (int)(v & (TBIN - 1));

        // q_phi row chunk: 8 lanes x 32B = contiguous 256B per query
        const float4* qp = (const float4*)(q_phi + (size_t)q * FEAT + h * 8);
        const float4 a0 = qp[0];
        const float4 a1 = qp[1];

        const float* lp = &lds[0][h * 8][dj];
        const float* ln = &lds[1][h * 8][dj];
        float sp = a0.x * lp[0]      + a0.y * lp[TP]     + a0.z * lp[2 * TP] + a0.w * lp[3 * TP]
                 + a1.x * lp[4 * TP] + a1.y * lp[5 * TP] + a1.z * lp[6 * TP] + a1.w * lp[7 * TP];
        float sn = a0.x * ln[0]      + a0.y * ln[TP]     + a0.z * ln[2 * TP] + a0.w * ln[3 * TP]
                 + a1.x * ln[4 * TP] + a1.y * ln[5 * TP] + a1.z * ln[6 * TP] + a1.w * ln[7 * TP];

        const int j = n0 + dj;
        const float dp = fmaxf(deg_pos[(size_t)j * H + h], 1.0f);
        const float dn = fmaxf(deg_neg[(size_t)j * H + h], 1.0f);

        if (valid) {
            const size_t o = (size_t)q * H + h;
            __builtin_nontemporal_store(sp / dp, &out[o]);
            __builtin_nontemporal_store(sn / dn, &out[(size_t)N_Q * H + o]);
        }
    }
}

// ---------------------------------------------------------------------------
// Fallback (no workspace): direct strided gather, wave per query.
// ---------------------------------------------------------------------------
__global__ __launch_bounds__(256, 4) void iskde_gather_kernel(
    const float* __restrict__ q_phi,
    const float* __restrict__ pk_pos,
    const float* __restrict__ pk_neg,
    const float* __restrict__ deg_pos,
    const float* __restrict__ deg_neg,
    const int*   __restrict__ k_idx,
    float*       __restrict__ out)
{
    const int wave_in_blk = threadIdx.x >> 6;
    const int lane        = threadIdx.x & 63;
    const int q           = blockIdx.x * 4 + wave_in_blk;
    if (q >= N_Q) return;

    const int j = k_idx[q];
    const float qv = q_phi[(size_t)q * FEAT + lane];
    const size_t col = (size_t)lane * (size_t)N_NODES + (size_t)j;
    const float pv = pk_pos[col];
    const float nv = pk_neg[col];

    float sp = qv * pv;
    float sn = qv * nv;
    sp += __shfl_xor(sp, 1, 64);
    sn += __shfl_xor(sn, 1, 64);
    sp += __shfl_xor(sp, 2, 64);
    sn += __shfl_xor(sn, 2, 64);
    sp += __shfl_xor(sp, 4, 64);
    sn += __shfl_xor(sn, 4, 64);

    if ((lane & 7) == 0) {
        const int h = lane >> 3;
        const float dp = fmaxf(deg_pos[(size_t)j * H + h], 1.0f);
        const float dn = fmaxf(deg_neg[(size_t)j * H + h], 1.0f);
        const size_t o = (size_t)q * H + h;
        out[o]                   = sp / dp;
        out[(size_t)N_Q * H + o] = sn / dn;
    }
}

extern "C" void kernel_launch(void* const* d_in, const int* in_sizes, int n_in,
                              void* d_out, int out_size, void* d_ws, size_t ws_size,
                              hipStream_t stream) {
    const float* q_phi   = (const float*)d_in[0];
    const float* pk_pos  = (const float*)d_in[1];
    const float* pk_neg  = (const float*)d_in[2];
    const float* deg_pos = (const float*)d_in[3];
    const float* deg_neg = (const float*)d_in[4];
    const int*   k_idx   = (const int*)d_in[5];
    float*       out     = (float*)d_out;

    // ws layout (ints): hist[NB_PAD] | offsets[NB_PAD+8] | cursor[NB_PAD+8] | vals[N_Q]
    const size_t need = ((size_t)NB_PAD * 3 + 16 + (size_t)N_Q) * sizeof(int);  // ~2.1 MB

    if (ws_size >= need) {
        int*      hist    = (int*)d_ws;
        int*      offsets = hist + NB_PAD;
        int*      cursor  = offsets + NB_PAD + 8;
        unsigned* vals    = (unsigned*)(cursor + NB_PAD + 8);

        zero_hist<<<(NB_PAD + 255) / 256, 256, 0, stream>>>(hist);
        hist_kernel<<<1024, 256, 0, stream>>>(k_idx, hist);
        scan_kernel<<<1, 1024, 0, stream>>>(hist, offsets, cursor);
        scatter_kernel<<<1024, 256, 0, stream>>>(k_idx, cursor, vals);
        iskde_binned<<<NB, 256, 0, stream>>>(
            q_phi, pk_pos, pk_neg, deg_pos, deg_neg, vals, offsets, out);
    } else {
        const int blocks = (N_Q + 3) / 4;
        iskde_gather_kernel<<<blocks, 256, 0, stream>>>(
            q_phi, pk_pos, pk_neg, deg_pos, deg_neg, k_idx, out);
    }
}

// Round 2
// 439.745 us; speedup vs baseline: 1.0682x; 1.0682x over previous
//
#include <hip/hip_runtime.h>

constexpr int N_NODES = 500000;
constexpr int N_Q     = 500000;
constexpr int H       = 8;
constexpr int FEAT    = 64;                       // H * MH

// ---- binning parameters -----------------------------------------------------
constexpr int TBIN   = 64;                        // nodes per bin
constexpr int SHIFT  = 6;                         // log2(TBIN)
constexpr int NB     = (N_NODES + TBIN - 1) / TBIN;   // 7813 bins
constexpr int NB_PAD = 8192;                      // scan width (1024 thr x 8)
constexpr int TP     = TBIN + 1;                  // 65: odd pad -> bank (f+dj)%32
constexpr int BT     = 512;                       // main-kernel block threads
constexpr int SLOTS  = BT / H;                    // 64 queries per sweep

// ---------------------------------------------------------------------------
// K0: zero the histogram (workspace is re-poisoned between iterations).
// ---------------------------------------------------------------------------
__global__ __launch_bounds__(256) void zero_hist(int* __restrict__ hist)
{
    const int i = blockIdx.x * 256 + threadIdx.x;
    if (i < NB_PAD) hist[i] = 0;
}

// ---------------------------------------------------------------------------
// K1: histogram of k_indices into node bins. Exact one-pass grid.
// ---------------------------------------------------------------------------
__global__ __launch_bounds__(256) void hist_kernel(const int* __restrict__ k_idx,
                                                   int* __restrict__ hist)
{
    const int i = blockIdx.x * 256 + threadIdx.x;
    if (i < N_Q) atomicAdd(&hist[k_idx[i] >> SHIFT], 1);
}

// ---------------------------------------------------------------------------
// K2: single-block exclusive scan over NB_PAD bins -> offsets (NB+1) & cursor.
// ---------------------------------------------------------------------------
__global__ __launch_bounds__(1024) void scan_kernel(const int* __restrict__ hist,
                                                    int* __restrict__ offsets,
                                                    int* __restrict__ cursor)
{
    __shared__ int sums[1024];
    const int tid  = threadIdx.x;
    const int base = tid * 8;

    int loc[8];
    int run = 0;
#pragma unroll
    for (int k = 0; k < 8; ++k) {
        loc[k] = run;
        const int idx = base + k;
        run += (idx < NB) ? hist[idx] : 0;
    }
    sums[tid] = run;
    __syncthreads();

    const int own = run;
    for (int d = 1; d < 1024; d <<= 1) {
        const int add = (tid >= d) ? sums[tid - d] : 0;
        __syncthreads();
        sums[tid] += add;
        __syncthreads();
    }
    const int excl = sums[tid] - own;

#pragma unroll
    for (int k = 0; k < 8; ++k) {
        const int idx = base + k;
        if (idx <= NB) {                     // offsets[NB] = N_Q (end sentinel)
            const int v = excl + loc[k];
            offsets[idx] = v;
            cursor[idx]  = v;
        }
    }
}

// ---------------------------------------------------------------------------
// K3: scatter packed (q << 6 | dj) into bin-sorted order. Exact one-pass grid.
// ---------------------------------------------------------------------------
__global__ __launch_bounds__(256) void scatter_kernel(const int* __restrict__ k_idx,
                                                      int* __restrict__ cursor,
                                                      unsigned* __restrict__ vals)
{
    const int i = blockIdx.x * 256 + threadIdx.x;
    if (i < N_Q) {
        const int j = k_idx[i];
        const int b = j >> SHIFT;
        const int p = atomicAdd(&cursor[b], 1);
        vals[p] = ((unsigned)i << SHIFT) | (unsigned)(j & (TBIN - 1));
    }
}

// ---------------------------------------------------------------------------
// K4: main binned kernel, v2.
//   * 512 threads -> 8 waves/block, 4 blocks/CU (LDS 33,280B) = 32 waves/CU.
//   * Sweep-0 gather (vals -> q_phi/deg) is issued BEFORE the staging barrier:
//     vmcnt waits oldest-first, so the dependent q_phi loads go out while the
//     staging loads are still in flight, and the barrier drain pays both
//     latencies concurrently instead of sequentially.
// ---------------------------------------------------------------------------
__global__ __launch_bounds__(BT, 8) void iskde_binned(
    const float* __restrict__ q_phi,
    const float* __restrict__ pk_pos,                 // [64][N_NODES]
    const float* __restrict__ pk_neg,
    const float* __restrict__ deg_pos,                // [N_NODES][H]
    const float* __restrict__ deg_neg,
    const unsigned* __restrict__ vals,                // bin-sorted (q<<6|dj)
    const int* __restrict__ offsets,                  // [NB+1]
    float* __restrict__ out)                          // [2][N_Q][H]
{
    __shared__ float lds[2][FEAT][TP];                // 33,280 B

    const int tid  = threadIdx.x;
    const int b    = blockIdx.x;
    const int n0   = b * TBIN;
    const int nrem = min(TBIN, N_NODES - n0);

    const int start = offsets[b];
    const int count = offsets[b + 1] - start;
    const int h    = tid & 7;
    const int slot = tid >> 3;                        // 0..63

    // ---- sweep-0 prefetch, part 1: issue the vals load first (oldest) ----
    const bool v0ok = slot < count;
    unsigned v0 = 0;
    if (v0ok) v0 = vals[start + slot];

    // ---- stage the bin's phi_k columns (pos & neg): 2048 float4 / 512 thr ----
#pragma unroll
    for (int it = 0; it < 4; ++it) {
        const int g  = it * BT + tid;                 // 0..2047
        const int s  = g >> 10;                       // 0..1
        const int f  = (g >> 4) & 63;                 // 0..63
        const int n4 = (g & 15) * 4;                  // 0..60
        const float* __restrict__ src = s ? pk_neg : pk_pos;
        const float* p = src + (size_t)f * N_NODES + n0 + n4;
        float4 w = make_float4(0.f, 0.f, 0.f, 0.f);
        if (n4 + 3 < nrem) {
            w = *(const float4*)p;
        } else {
            if (n4 + 0 < nrem) w.x = p[0];
            if (n4 + 1 < nrem) w.y = p[1];
            if (n4 + 2 < nrem) w.z = p[2];
        }
        float* l = &lds[s][f][n4];
        l[0] = w.x; l[1] = w.y; l[2] = w.z; l[3] = w.w;
    }

    // ---- sweep-0 prefetch, part 2: dependent gathers, still pre-barrier ----
    // (waiting on v0 only waits the oldest load; staging stays in flight)
    const int q0  = (int)(v0 >> SHIFT);               // invalid lanes -> q=0, safe
    const int dj0 = (int)(v0 & (TBIN - 1));
    const float4* qp0 = (const float4*)(q_phi + (size_t)q0 * FEAT + h * 8);
    const float4 a0 = qp0[0];
    const float4 a1 = qp0[1];
    const int   j0   = n0 + dj0;
    const float dgp0 = deg_pos[(size_t)j0 * H + h];
    const float dgn0 = deg_neg[(size_t)j0 * H + h];

    __syncthreads();

    // ---- sweep 0 compute ----
    if (v0ok) {
        const float* lp = &lds[0][h * 8][dj0];
        const float* ln = &lds[1][h * 8][dj0];
        float sp = a0.x * lp[0]      + a0.y * lp[TP]     + a0.z * lp[2 * TP] + a0.w * lp[3 * TP]
                 + a1.x * lp[4 * TP] + a1.y * lp[5 * TP] + a1.z * lp[6 * TP] + a1.w * lp[7 * TP];
        float sn = a0.x * ln[0]      + a0.y * ln[TP]     + a0.z * ln[2 * TP] + a0.w * ln[3 * TP]
                 + a1.x * ln[4 * TP] + a1.y * ln[5 * TP] + a1.z * ln[6 * TP] + a1.w * ln[7 * TP];
        const float dp = fmaxf(dgp0, 1.0f);
        const float dn = fmaxf(dgn0, 1.0f);
        const size_t o = (size_t)q0 * H + h;
        __builtin_nontemporal_store(sp / dp, &out[o]);
        __builtin_nontemporal_store(sn / dn, &out[(size_t)N_Q * H + o]);
    }

    // ---- remaining sweeps (less common: Poisson(64) tail) ----
    for (int it0 = SLOTS; it0 < count; it0 += SLOTS) {
        const int qi     = it0 + slot;
        const bool valid = qi < count;
        unsigned v = 0;
        if (valid) v = vals[start + qi];
        const int q  = (int)(v >> SHIFT);
        const int dj = (int)(v & (TBIN - 1));

        const float4* qp = (const float4*)(q_phi + (size_t)q * FEAT + h * 8);
        const float4 b0 = qp[0];
        const float4 b1 = qp[1];

        const float* lp = &lds[0][h * 8][dj];
        const float* ln = &lds[1][h * 8][dj];
        float sp = b0.x * lp[0]      + b0.y * lp[TP]     + b0.z * lp[2 * TP] + b0.w * lp[3 * TP]
                 + b1.x * lp[4 * TP] + b1.y * lp[5 * TP] + b1.z * lp[6 * TP] + b1.w * lp[7 * TP];
        float sn = b0.x * ln[0]      + b0.y * ln[TP]     + b0.z * ln[2 * TP] + b0.w * ln[3 * TP]
                 + b1.x * ln[4 * TP] + b1.y * ln[5 * TP] + b1.z * ln[6 * TP] + b1.w * ln[7 * TP];

        const int j = n0 + dj;
        const float dp = fmaxf(deg_pos[(size_t)j * H + h], 1.0f);
        const float dn = fmaxf(deg_neg[(size_t)j * H + h], 1.0f);

        if (valid) {
            const size_t o = (size_t)q * H + h;
            __builtin_nontemporal_store(sp / dp, &out[o]);
            __builtin_nontemporal_store(sn / dn, &out[(size_t)N_Q * H + o]);
        }
    }
}

// ---------------------------------------------------------------------------
// Fallback (no workspace): direct strided gather, wave per query.
// ---------------------------------------------------------------------------
__global__ __launch_bounds__(256, 4) void iskde_gather_kernel(
    const float* __restrict__ q_phi,
    const float* __restrict__ pk_pos,
    const float* __restrict__ pk_neg,
    const float* __restrict__ deg_pos,
    const float* __restrict__ deg_neg,
    const int*   __restrict__ k_idx,
    float*       __restrict__ out)
{
    const int wave_in_blk = threadIdx.x >> 6;
    const int lane        = threadIdx.x & 63;
    const int q           = blockIdx.x * 4 + wave_in_blk;
    if (q >= N_Q) return;

    const int j = k_idx[q];
    const float qv = q_phi[(size_t)q * FEAT + lane];
    const size_t col = (size_t)lane * (size_t)N_NODES + (size_t)j;
    const float pv = pk_pos[col];
    const float nv = pk_neg[col];

    float sp = qv * pv;
    float sn = qv * nv;
    sp += __shfl_xor(sp, 1, 64);
    sn += __shfl_xor(sn, 1, 64);
    sp += __shfl_xor(sp, 2, 64);
    sn += __shfl_xor(sn, 2, 64);
    sp += __shfl_xor(sp, 4, 64);
    sn += __shfl_xor(sn, 4, 64);

    if ((lane & 7) == 0) {
        const int h = lane >> 3;
        const float dp = fmaxf(deg_pos[(size_t)j * H + h], 1.0f);
        const float dn = fmaxf(deg_neg[(size_t)j * H + h], 1.0f);
        const size_t o = (size_t)q * H + h;
        out[o]                   = sp / dp;
        out[(size_t)N_Q * H + o] = sn / dn;
    }
}

extern "C" void kernel_launch(void* const* d_in, const int* in_sizes, int n_in,
                              void* d_out, int out_size, void* d_ws, size_t ws_size,
                              hipStream_t stream) {
    const float* q_phi   = (const float*)d_in[0];
    const float* pk_pos  = (const float*)d_in[1];
    const float* pk_neg  = (const float*)d_in[2];
    const float* deg_pos = (const float*)d_in[3];
    const float* deg_neg = (const float*)d_in[4];
    const int*   k_idx   = (const int*)d_in[5];
    float*       out     = (float*)d_out;

    // ws layout (ints): hist[NB_PAD] | offsets[NB_PAD+8] | cursor[NB_PAD+8] | vals[N_Q]
    const size_t need = ((size_t)NB_PAD * 3 + 16 + (size_t)N_Q) * sizeof(int);  // ~2.1 MB

    if (ws_size >= need) {
        int*      hist    = (int*)d_ws;
        int*      offsets = hist + NB_PAD;
        int*      cursor  = offsets + NB_PAD + 8;
        unsigned* vals    = (unsigned*)(cursor + NB_PAD + 8);

        const int qblocks = (N_Q + 255) / 256;        // 1954, one item/thread
        zero_hist<<<(NB_PAD + 255) / 256, 256, 0, stream>>>(hist);
        hist_kernel<<<qblocks, 256, 0, stream>>>(k_idx, hist);
        scan_kernel<<<1, 1024, 0, stream>>>(hist, offsets, cursor);
        scatter_kernel<<<qblocks, 256, 0, stream>>>(k_idx, cursor, vals);
        iskde_binned<<<NB, BT, 0, stream>>>(
            q_phi, pk_pos, pk_neg, deg_pos, deg_neg, vals, offsets, out);
    } else {
        const int blocks = (N_Q + 3) / 4;
        iskde_gather_kernel<<<blocks, 256, 0, stream>>>(
            q_phi, pk_pos, pk_neg, deg_pos, deg_neg, k_idx, out);
    }
}